// Round 1
// baseline (288.258 us; speedup 1.0000x reference)
//
#include <hip/hip_runtime.h>
#include <hip/hip_bf16.h>
#include <cstdint>
#include <cstddef>

typedef __bf16 bf16_t;
typedef __bf16 bf16x8 __attribute__((ext_vector_type(8)));
typedef __bf16 bf16x4 __attribute__((ext_vector_type(4)));
typedef float f32x4 __attribute__((ext_vector_type(4)));

#define NB 2
#define NT 2048
#define NC 1024
#define NH 16
#define ND 64
#define NM (NB * NT)   // 4096
#define N3 (3 * NC)    // 3072
#define ATT_SCALE 0.125f

// async global->LDS, 16B per lane; LDS dest is wave-uniform base + lane*16
#define GLOAD_LDS16(gptr, lptr)                                                          \
  __builtin_amdgcn_global_load_lds((const __attribute__((address_space(1))) void*)(gptr), \
                                   (__attribute__((address_space(3))) void*)(lptr), 16, 0, 0)

// ---------------------------------------------------------------- casts
__global__ __launch_bounds__(256) void cast_f32_bf16_k(const float* __restrict__ in,
                                                       bf16_t* __restrict__ out, int n) {
  int i = (blockIdx.x * 256 + threadIdx.x) * 4;
  if (i + 3 < n) {
    const float4 v = *(const float4*)(in + i);
    bf16x4 o;
    o[0] = (bf16_t)v.x; o[1] = (bf16_t)v.y; o[2] = (bf16_t)v.z; o[3] = (bf16_t)v.w;
    *(bf16x4*)(out + i) = o;
  }
}

// out[c][r] = (bf16) in[r][c]   (in: R x Ccols fp32) -> B^T layout for GEMM
__global__ __launch_bounds__(256) void transpose_cast_k(const float* __restrict__ in,
                                                        bf16_t* __restrict__ out,
                                                        int R, int Ccols) {
  __shared__ float tile[32][33];
  int tc = blockIdx.x * 32;
  int tr = blockIdx.y * 32;
  int lx = threadIdx.x & 31;
  int ly = threadIdx.x >> 5;
#pragma unroll
  for (int i = 0; i < 32; i += 8)
    tile[ly + i][lx] = in[(size_t)(tr + ly + i) * Ccols + tc + lx];
  __syncthreads();
#pragma unroll
  for (int i = 0; i < 32; i += 8)
    out[(size_t)(tc + ly + i) * R + tr + lx] = (bf16_t)tile[lx][ly + i];
}

// ---------------------------------------------------------------- GEMM mainloop
// C[m,n] = sum_k A[m,k] * Bt[n,k]; A:[M,K] bf16, Bt:[N,K] bf16. 128x128 tile, 4 waves.
template <int K>
__device__ __forceinline__ void gemm_mainloop(const bf16_t* __restrict__ A,
                                              const bf16_t* __restrict__ Bt,
                                              int m0, int n0, f32x4 acc[4][4],
                                              bf16_t* lds) {
  bf16_t* As = lds;         // [128][32]
  bf16_t* Bs = lds + 4096;  // [128][32]
  const int tid = threadIdx.x;
  const int lane = tid & 63;
  const int w = tid >> 6;
  const int wm = (w & 1) * 64;
  const int wn = (w >> 1) * 64;
  const int quad = lane >> 4;
  const int l16 = lane & 15;

  for (int k0 = 0; k0 < K; k0 += 32) {
#pragma unroll
    for (int i = 0; i < 2; ++i) {
      const int gb = w * 128 + i * 64;   // group base (8 bf16 per group)
      const int g = gb + lane;
      GLOAD_LDS16(A + (size_t)(m0 + (g >> 2)) * K + k0 + (g & 3) * 8, As + gb * 8);
      GLOAD_LDS16(Bt + (size_t)(n0 + (g >> 2)) * K + k0 + (g & 3) * 8, Bs + gb * 8);
    }
    __syncthreads();
    bf16x8 af[4], bfr[4];
#pragma unroll
    for (int i = 0; i < 4; ++i)
      af[i] = *(const bf16x8*)(As + (wm + i * 16 + l16) * 32 + quad * 8);
#pragma unroll
    for (int j = 0; j < 4; ++j)
      bfr[j] = *(const bf16x8*)(Bs + (wn + j * 16 + l16) * 32 + quad * 8);
#pragma unroll
    for (int i = 0; i < 4; ++i)
#pragma unroll
      for (int j = 0; j < 4; ++j)
        acc[i][j] = __builtin_amdgcn_mfma_f32_16x16x32_bf16(af[i], bfr[j], acc[i][j], 0, 0, 0);
    __syncthreads();
  }
}

// ---------------------------------------------------------------- QKV GEMM
// A = x bf16 [4096,1024]; Bt = Wqkv^T [3072,1024]. Epilogue scatters to q,k:[B,H,T,D], vT:[B,H,D,T]
__global__ __launch_bounds__(256) void qkv_gemm_k(const bf16_t* __restrict__ A,
                                                  const bf16_t* __restrict__ Bt,
                                                  const float* __restrict__ bias,
                                                  bf16_t* __restrict__ qb,
                                                  bf16_t* __restrict__ kb,
                                                  bf16_t* __restrict__ vtb) {
  __shared__ __align__(16) bf16_t lds[8192];
  const int m0 = blockIdx.y * 128, n0 = blockIdx.x * 128;
  f32x4 acc[4][4] = {};
  gemm_mainloop<NC>(A, Bt, m0, n0, acc, lds);

  const int lane = threadIdx.x & 63;
  const int w = threadIdx.x >> 6;
  const int wm = (w & 1) * 64, wn = (w >> 1) * 64;
  const int quad = lane >> 4, l16 = lane & 15;
#pragma unroll
  for (int i = 0; i < 4; ++i)
#pragma unroll
    for (int j = 0; j < 4; ++j) {
      const int n = n0 + wn + j * 16 + l16;
      const float bn = bias[n];
      const int which = n >> 10;        // 0=q 1=k 2=v
      const int rem = n & 1023;
      const int h = rem >> 6, d = rem & 63;
#pragma unroll
      for (int r = 0; r < 4; ++r) {
        const int m = m0 + wm + i * 16 + quad * 4 + r;  // C/D: row=(lane>>4)*4+reg
        const int b = m >> 11, t = m & 2047;
        const bf16_t val = (bf16_t)(acc[i][j][r] + bn);
        const size_t bh = (size_t)b * NH + h;
        if (which == 0)
          qb[(bh * NT + t) * ND + d] = val;
        else if (which == 1)
          kb[(bh * NT + t) * ND + d] = val;
        else
          vtb[(bh * ND + d) * NT + t] = val;
      }
    }
}

// ---------------------------------------------------------------- attention
// mask keeps k >= q (upper triangular). Block: one (b,h) x 64 q-rows; wave: 16 q-rows.
__global__ __launch_bounds__(256) void attn_k(const bf16_t* __restrict__ q,
                                              const bf16_t* __restrict__ k,
                                              const bf16_t* __restrict__ vt,
                                              bf16_t* __restrict__ y /*[B,T,C]*/) {
  const int qt = blockIdx.x & 31;   // q-tile (64 rows)
  const int bh = blockIdx.x >> 5;   // 0..31
  const int b = bh >> 4, h = bh & 15;
  const int q0 = qt * 64;
  const bf16_t* qp = q + (size_t)bh * NT * ND;
  const bf16_t* kp = k + (size_t)bh * NT * ND;
  const bf16_t* vp = vt + (size_t)bh * ND * NT;

  __shared__ __align__(16) bf16_t kt[64 * 64];     // [t_rel][d]
  __shared__ __align__(16) bf16_t vtile[64 * 64];  // [d][t_rel]
  __shared__ __align__(16) bf16_t pt[4][16 * 72];  // per-wave P [16][72] (+8 pad)

  const int lane = threadIdx.x & 63;
  const int w = threadIdx.x >> 6;
  const int quad = lane >> 4, l16 = lane & 15;
  const int qw = q0 + w * 16;  // wave's q base

  // Q fragments (2 d-halves), reused across all chunks
  bf16x8 qf[2];
#pragma unroll
  for (int hh = 0; hh < 2; ++hh)
    qf[hh] = *(const bf16x8*)(qp + (size_t)(qw + l16) * ND + hh * 32 + quad * 8);

  float mrow[4], lrow[4];
  f32x4 accO[4];
#pragma unroll
  for (int r = 0; r < 4; ++r) { mrow[r] = -INFINITY; lrow[r] = 0.f; }
#pragma unroll
  for (int j = 0; j < 4; ++j) accO[j] = (f32x4){0.f, 0.f, 0.f, 0.f};

  for (int t0 = q0; t0 < NT; t0 += 64) {
    // stage K chunk [64][64] and V chunk [64][64]
#pragma unroll
    for (int i = 0; i < 2; ++i) {
      const int gb = w * 128 + i * 64;
      const int g = gb + lane;
      GLOAD_LDS16(kp + (size_t)(t0 + (g >> 3)) * ND + (g & 7) * 8, kt + gb * 8);
      GLOAD_LDS16(vp + (size_t)(g >> 3) * NT + t0 + (g & 7) * 8, vtile + gb * 8);
    }
    __syncthreads();

    // S = Q K^T : 4 key-tiles of 16, each accumulated over 2 d-halves
    float sv[4][4];
#pragma unroll
    for (int j = 0; j < 4; ++j) {
      f32x4 z = {0.f, 0.f, 0.f, 0.f};
      bf16x8 b0 = *(const bf16x8*)(kt + (j * 16 + l16) * 64 + quad * 8);
      z = __builtin_amdgcn_mfma_f32_16x16x32_bf16(qf[0], b0, z, 0, 0, 0);
      bf16x8 b1 = *(const bf16x8*)(kt + (j * 16 + l16) * 64 + 32 + quad * 8);
      z = __builtin_amdgcn_mfma_f32_16x16x32_bf16(qf[1], b1, z, 0, 0, 0);
#pragma unroll
      for (int r = 0; r < 4; ++r) sv[j][r] = z[r] * ATT_SCALE;
    }
    // mask only on the diagonal chunk (t0 == q0); later chunks fully allowed (k >= q)
    if (t0 == q0) {
#pragma unroll
      for (int j = 0; j < 4; ++j)
#pragma unroll
        for (int r = 0; r < 4; ++r) {
          const int qi = qw + quad * 4 + r;
          const int ki = t0 + j * 16 + l16;
          if (ki < qi) sv[j][r] = -INFINITY;
        }
    }
    // row max (over 4 tiles then 16 lanes of the quad-group)
    float alpha[4];
#pragma unroll
    for (int r = 0; r < 4; ++r) {
      float mx = fmaxf(fmaxf(sv[0][r], sv[1][r]), fmaxf(sv[2][r], sv[3][r]));
#pragma unroll
      for (int off = 1; off < 16; off <<= 1) mx = fmaxf(mx, __shfl_xor(mx, off, 64));
      const float mnew = fmaxf(mrow[r], mx);
      alpha[r] = __expf(mrow[r] - mnew);  // first chunk: exp(-inf)=0
      mrow[r] = mnew;
    }
    // P = exp(S - m), row sums, write P to LDS (A-layout source)
    float rsum[4] = {0.f, 0.f, 0.f, 0.f};
#pragma unroll
    for (int j = 0; j < 4; ++j)
#pragma unroll
      for (int r = 0; r < 4; ++r) {
        const float p = __expf(sv[j][r] - mrow[r]);
        sv[j][r] = p;
        rsum[r] += p;
      }
#pragma unroll
    for (int r = 0; r < 4; ++r) {
      float s_ = rsum[r];
#pragma unroll
      for (int off = 1; off < 16; off <<= 1) s_ += __shfl_xor(s_, off, 64);
      lrow[r] = lrow[r] * alpha[r] + s_;
    }
#pragma unroll
    for (int j = 0; j < 4; ++j)
#pragma unroll
      for (int r = 0; r < 4; ++r)
        pt[w][(quad * 4 + r) * 72 + j * 16 + l16] = (bf16_t)sv[j][r];
    // rescale O accumulator
#pragma unroll
    for (int j = 0; j < 4; ++j)
#pragma unroll
      for (int r = 0; r < 4; ++r) accO[j][r] *= alpha[r];
    __asm__ volatile("s_waitcnt lgkmcnt(0)" ::: "memory");  // P write -> P read (wave-local)
    // O += P V : d-chunks of 16, k-chunks of 32
#pragma unroll
    for (int j = 0; j < 4; ++j)
#pragma unroll
      for (int kk = 0; kk < 2; ++kk) {
        bf16x8 a = *(const bf16x8*)(&pt[w][l16 * 72 + kk * 32 + quad * 8]);
        bf16x8 bb = *(const bf16x8*)(vtile + (j * 16 + l16) * 64 + kk * 32 + quad * 8);
        accO[j] = __builtin_amdgcn_mfma_f32_16x16x32_bf16(a, bb, accO[j], 0, 0, 0);
      }
    __syncthreads();  // all waves done with kt/vtile before next stage
  }

  // normalize + store y [B,T,C] bf16
#pragma unroll
  for (int r = 0; r < 4; ++r) {
    const float inv = 1.0f / lrow[r];
    const int t = qw + quad * 4 + r;
    const size_t base = ((size_t)b * NT + t) * NC + h * 64;
#pragma unroll
    for (int j = 0; j < 4; ++j)
      y[base + j * 16 + l16] = (bf16_t)(accO[j][r] * inv);
  }
}

// ---------------------------------------------------------------- out projection
__global__ __launch_bounds__(256) void out_gemm_k(const bf16_t* __restrict__ A,
                                                  const bf16_t* __restrict__ Bt,
                                                  const float* __restrict__ bias,
                                                  float* __restrict__ out) {
  __shared__ __align__(16) bf16_t lds[8192];
  const int m0 = blockIdx.y * 128, n0 = blockIdx.x * 128;
  f32x4 acc[4][4] = {};
  gemm_mainloop<NC>(A, Bt, m0, n0, acc, lds);

  const int lane = threadIdx.x & 63;
  const int w = threadIdx.x >> 6;
  const int wm = (w & 1) * 64, wn = (w >> 1) * 64;
  const int quad = lane >> 4, l16 = lane & 15;
#pragma unroll
  for (int i = 0; i < 4; ++i)
#pragma unroll
    for (int j = 0; j < 4; ++j) {
      const int n = n0 + wn + j * 16 + l16;
      const float bn = bias[n];
#pragma unroll
      for (int r = 0; r < 4; ++r) {
        const int m = m0 + wm + i * 16 + quad * 4 + r;
        out[(size_t)m * NC + n] = acc[i][j][r] + bn;
      }
    }
}

// ---------------------------------------------------------------- launch
extern "C" void kernel_launch(void* const* d_in, const int* in_sizes, int n_in,
                              void* d_out, int out_size, void* d_ws, size_t ws_size,
                              hipStream_t stream) {
  const float* x = (const float*)d_in[0];
  const float* Wqkv = (const float*)d_in[1];
  const float* bqkv = (const float*)d_in[2];
  const float* Wo = (const float*)d_in[3];
  const float* bo = (const float*)d_in[4];
  float* out = (float*)d_out;

  char* p = (char*)d_ws;
  bf16_t* xbf = (bf16_t*)p;   p += (size_t)NM * NC * sizeof(bf16_t);        // 8 MB
  bf16_t* wqkvT = (bf16_t*)p; p += (size_t)N3 * NC * sizeof(bf16_t);        // 6 MB
  bf16_t* woT = (bf16_t*)p;   p += (size_t)NC * NC * sizeof(bf16_t);        // 2 MB
  bf16_t* qb = (bf16_t*)p;    p += (size_t)NB * NH * NT * ND * sizeof(bf16_t); // 8 MB
  bf16_t* kb = (bf16_t*)p;    p += (size_t)NB * NH * NT * ND * sizeof(bf16_t); // 8 MB
  bf16_t* vtb = (bf16_t*)p;   p += (size_t)NB * NH * ND * NT * sizeof(bf16_t); // 8 MB
  bf16_t* yb = (bf16_t*)p;    p += (size_t)NM * NC * sizeof(bf16_t);        // 8 MB

  hipLaunchKernelGGL(cast_f32_bf16_k, dim3(NM * NC / 1024), dim3(256), 0, stream,
                     x, xbf, NM * NC);
  hipLaunchKernelGGL(transpose_cast_k, dim3(N3 / 32, NC / 32), dim3(256), 0, stream,
                     Wqkv, wqkvT, NC, N3);
  hipLaunchKernelGGL(transpose_cast_k, dim3(NC / 32, NC / 32), dim3(256), 0, stream,
                     Wo, woT, NC, NC);
  hipLaunchKernelGGL(qkv_gemm_k, dim3(N3 / 128, NM / 128), dim3(256), 0, stream,
                     xbf, wqkvT, bqkv, qb, kb, vtb);
  hipLaunchKernelGGL(attn_k, dim3(NB * NH * (NT / 64)), dim3(256), 0, stream,
                     qb, kb, vtb, yb);
  hipLaunchKernelGGL(out_gemm_k, dim3(NC / 128, NM / 128), dim3(256), 0, stream,
                     yb, woT, bo, out);
}

// Round 2
// 204.805 us; speedup vs baseline: 1.4075x; 1.4075x over previous
//
#include <hip/hip_runtime.h>
#include <hip/hip_bf16.h>
#include <cstdint>
#include <cstddef>

typedef __bf16 bf16_t;
typedef __bf16 bf16x8 __attribute__((ext_vector_type(8)));
typedef __bf16 bf16x4 __attribute__((ext_vector_type(4)));
typedef short short4v __attribute__((ext_vector_type(4)));
typedef float f32x4 __attribute__((ext_vector_type(4)));

#define NB 2
#define NT 2048
#define NC 1024
#define NH 16
#define ND 64
#define NM (NB * NT)   // 4096
#define N3 (3 * NC)    // 3072
#define ATT_SCALE 0.125f

// async global->LDS, 16B per lane; LDS dest is wave-uniform base + lane*16
#define GLOAD_LDS16(gptr, lptr)                                                          \
  __builtin_amdgcn_global_load_lds((const __attribute__((address_space(1))) void*)(gptr), \
                                   (__attribute__((address_space(3))) void*)(lptr), 16, 0, 0)

// ---------------------------------------------------------------- casts
__global__ __launch_bounds__(256) void cast_f32_bf16_k(const float* __restrict__ in,
                                                       bf16_t* __restrict__ out, int n) {
  int i = (blockIdx.x * 256 + threadIdx.x) * 4;
  if (i + 3 < n) {
    const float4 v = *(const float4*)(in + i);
    bf16x4 o;
    o[0] = (bf16_t)v.x; o[1] = (bf16_t)v.y; o[2] = (bf16_t)v.z; o[3] = (bf16_t)v.w;
    *(bf16x4*)(out + i) = o;
  }
}

// out[c][r] = (bf16) in[r][c]   (in: R x Ccols fp32) -> B^T layout for GEMM
__global__ __launch_bounds__(256) void transpose_cast_k(const float* __restrict__ in,
                                                        bf16_t* __restrict__ out,
                                                        int R, int Ccols) {
  __shared__ float tile[32][33];
  int tc = blockIdx.x * 32;
  int tr = blockIdx.y * 32;
  int lx = threadIdx.x & 31;
  int ly = threadIdx.x >> 5;
#pragma unroll
  for (int i = 0; i < 32; i += 8)
    tile[ly + i][lx] = in[(size_t)(tr + ly + i) * Ccols + tc + lx];
  __syncthreads();
#pragma unroll
  for (int i = 0; i < 32; i += 8)
    out[(size_t)(tc + ly + i) * R + tr + lx] = (bf16_t)tile[lx][ly + i];
}

// ---------------------------------------------------------------- GEMM mainloop
// C[m,n] = sum_k A[m,k] * Bt[n,k]; A:[M,K] bf16, Bt:[N,K] bf16. 128x128 tile, 4 waves.
template <int K>
__device__ __forceinline__ void gemm_mainloop(const bf16_t* __restrict__ A,
                                              const bf16_t* __restrict__ Bt,
                                              int m0, int n0, f32x4 acc[4][4],
                                              bf16_t* lds) {
  bf16_t* As = lds;         // [128][32]
  bf16_t* Bs = lds + 4096;  // [128][32]
  const int tid = threadIdx.x;
  const int lane = tid & 63;
  const int w = tid >> 6;
  const int wm = (w & 1) * 64;
  const int wn = (w >> 1) * 64;
  const int quad = lane >> 4;
  const int l16 = lane & 15;

  for (int k0 = 0; k0 < K; k0 += 32) {
#pragma unroll
    for (int i = 0; i < 2; ++i) {
      const int gb = w * 128 + i * 64;   // group base (8 bf16 per group)
      const int g = gb + lane;
      GLOAD_LDS16(A + (size_t)(m0 + (g >> 2)) * K + k0 + (g & 3) * 8, As + gb * 8);
      GLOAD_LDS16(Bt + (size_t)(n0 + (g >> 2)) * K + k0 + (g & 3) * 8, Bs + gb * 8);
    }
    __syncthreads();
    bf16x8 af[4], bfr[4];
#pragma unroll
    for (int i = 0; i < 4; ++i)
      af[i] = *(const bf16x8*)(As + (wm + i * 16 + l16) * 32 + quad * 8);
#pragma unroll
    for (int j = 0; j < 4; ++j)
      bfr[j] = *(const bf16x8*)(Bs + (wn + j * 16 + l16) * 32 + quad * 8);
#pragma unroll
    for (int i = 0; i < 4; ++i)
#pragma unroll
      for (int j = 0; j < 4; ++j)
        acc[i][j] = __builtin_amdgcn_mfma_f32_16x16x32_bf16(af[i], bfr[j], acc[i][j], 0, 0, 0);
    __syncthreads();
  }
}

// ---------------------------------------------------------------- QKV GEMM
// A = x bf16 [4096,1024]; Bt = Wqkv^T [3072,1024]. q is PRE-SCALED by 1/sqrt(D).
// Epilogue scatters to q,k:[B,H,T,D], vT:[B,H,D,T]
__global__ __launch_bounds__(256) void qkv_gemm_k(const bf16_t* __restrict__ A,
                                                  const bf16_t* __restrict__ Bt,
                                                  const float* __restrict__ bias,
                                                  bf16_t* __restrict__ qb,
                                                  bf16_t* __restrict__ kb,
                                                  bf16_t* __restrict__ vtb) {
  __shared__ __align__(16) bf16_t lds[8192];
  const int m0 = blockIdx.y * 128, n0 = blockIdx.x * 128;
  f32x4 acc[4][4] = {};
  gemm_mainloop<NC>(A, Bt, m0, n0, acc, lds);

  const int lane = threadIdx.x & 63;
  const int w = threadIdx.x >> 6;
  const int wm = (w & 1) * 64, wn = (w >> 1) * 64;
  const int quad = lane >> 4, l16 = lane & 15;
#pragma unroll
  for (int i = 0; i < 4; ++i)
#pragma unroll
    for (int j = 0; j < 4; ++j) {
      const int n = n0 + wn + j * 16 + l16;
      const float bn = bias[n];
      const int which = n >> 10;        // 0=q 1=k 2=v
      const int rem = n & 1023;
      const int h = rem >> 6, d = rem & 63;
#pragma unroll
      for (int r = 0; r < 4; ++r) {
        const int m = m0 + wm + i * 16 + quad * 4 + r;  // C/D: row=(lane>>4)*4+reg
        const int b = m >> 11, t = m & 2047;
        float v = acc[i][j][r] + bn;
        if (which == 0) v *= ATT_SCALE;
        const bf16_t val = (bf16_t)v;
        const size_t bh = (size_t)b * NH + h;
        if (which == 0)
          qb[(bh * NT + t) * ND + d] = val;
        else if (which == 1)
          kb[(bh * NT + t) * ND + d] = val;
        else
          vtb[(bh * ND + d) * NT + t] = val;
      }
    }
}

// ---------------------------------------------------------------- attention v2
// S^T formulation: each lane owns one query (l16). P^T (C-layout of S^T) is exactly
// the B-operand layout of mfma_f32_16x16x16_bf16, so PV needs no LDS round-trip.
// Block = one (b,h) x TWO q-tiles (a, 31-a) sharing one K/V chunk stream.
// K/V staged with XOR swizzle (granule c stored at c^(row&7)) -> conflict-free reads.

__device__ __forceinline__ void attn_step(const bf16x8 qf[2],
                                          float& m, float& l, f32x4 o[4],
                                          int qv /*absolute query idx of this lane*/,
                                          int t0, bool diag,
                                          const bf16_t* kt, const bf16_t* vt,
                                          int quad, int l16) {
  f32x4 sv[4];
#pragma unroll
  for (int kj = 0; kj < 4; ++kj) {
    const int kr = kj * 16 + l16;
    const int sw = kr & 7;
    f32x4 z = {0.f, 0.f, 0.f, 0.f};
    const bf16x8 a0 = *(const bf16x8*)(kt + (kr * 8 + (quad ^ sw)) * 8);
    z = __builtin_amdgcn_mfma_f32_16x16x32_bf16(a0, qf[0], z, 0, 0, 0);
    const bf16x8 a1 = *(const bf16x8*)(kt + (kr * 8 + ((4 + quad) ^ sw)) * 8);
    z = __builtin_amdgcn_mfma_f32_16x16x32_bf16(a1, qf[1], z, 0, 0, 0);
    sv[kj] = z;  // S^T: row(key)=quad*4+r within kj-subtile, col(query)=l16
  }
  if (diag) {
#pragma unroll
    for (int kj = 0; kj < 4; ++kj)
#pragma unroll
      for (int r = 0; r < 4; ++r)
        if (t0 + kj * 16 + quad * 4 + r < qv) sv[kj][r] = -INFINITY;
  }
  // row (query) max: local over 16 regs, then across the 4 quads
  float mx = -INFINITY;
#pragma unroll
  for (int kj = 0; kj < 4; ++kj)
#pragma unroll
    for (int r = 0; r < 4; ++r) mx = fmaxf(mx, sv[kj][r]);
  mx = fmaxf(mx, __shfl_xor(mx, 16));
  mx = fmaxf(mx, __shfl_xor(mx, 32));
  const float mnew = fmaxf(m, mx);
  const float alpha = __expf(m - mnew);
  m = mnew;
  float s = 0.f;
#pragma unroll
  for (int kj = 0; kj < 4; ++kj)
#pragma unroll
    for (int r = 0; r < 4; ++r) {
      const float p = __expf(sv[kj][r] - mnew);
      sv[kj][r] = p;
      s += p;
    }
  s += __shfl_xor(s, 16);
  s += __shfl_xor(s, 32);
  l = l * alpha + s;
  // pack P^T as x16 B-frags (k = quad*4+i, n = l16) -- already in-lane!
  short4v pf[4];
#pragma unroll
  for (int kj = 0; kj < 4; ++kj) {
    bf16x4 pb;
#pragma unroll
    for (int r = 0; r < 4; ++r) pb[r] = (bf16_t)sv[kj][r];
    pf[kj] = __builtin_bit_cast(short4v, pb);
  }
  // O^T += V^T * P^T  (x16 MFMAs; A = V^T frag: m=d(l16), k=key(quad*4+i))
#pragma unroll
  for (int dj = 0; dj < 4; ++dj) {
    o[dj][0] *= alpha; o[dj][1] *= alpha; o[dj][2] *= alpha; o[dj][3] *= alpha;
    const int dr = dj * 16 + l16;
    const int sw = dr & 7;
#pragma unroll
    for (int kj = 0; kj < 4; ++kj) {
      const int kc = kj * 2 + (quad >> 1);
      const bf16x4 a = *(const bf16x4*)(vt + (dr * 8 + (kc ^ sw)) * 8 + (quad & 1) * 4);
      o[dj] = __builtin_amdgcn_mfma_f32_16x16x16bf16_1k(
          __builtin_bit_cast(short4v, a), pf[kj], o[dj], 0, 0, 0);
    }
  }
}

__global__ __launch_bounds__(256) void attn_k(const bf16_t* __restrict__ q,
                                              const bf16_t* __restrict__ k,
                                              const bf16_t* __restrict__ vt,
                                              bf16_t* __restrict__ y /*[B,T,C]*/) {
  const int bh = blockIdx.x >> 4;               // 0..31
  const int p0 = blockIdx.x & 15;
  const int pair = ((blockIdx.x >> 8) & 1) ? (15 - p0) : p0;  // balance c & c+256
  const int tA = pair, tB = 31 - pair;
  const int qA0 = tA * 64, qB0 = tB * 64;
  const int b = bh >> 4, h = bh & 15;
  const bf16_t* qp = q + (size_t)bh * NT * ND;
  const bf16_t* kp = k + (size_t)bh * NT * ND;
  const bf16_t* vp = vt + (size_t)bh * ND * NT;

  __shared__ __align__(16) bf16_t kt[64 * 64];
  __shared__ __align__(16) bf16_t vtile[64 * 64];

  const int lane = threadIdx.x & 63;
  const int w = threadIdx.x >> 6;
  const int quad = lane >> 4, l16 = lane & 15;
  const int qa = qA0 + w * 16 + l16;  // this lane's query (tile A)
  const int qb2 = qB0 + w * 16 + l16; // this lane's query (tile B)

  // Q fragments (B-operand of x32 S^T MFMA): lane l16 holds query, k=quad*8+i
  bf16x8 qfA[2], qfB[2];
#pragma unroll
  for (int hh = 0; hh < 2; ++hh) {
    qfA[hh] = *(const bf16x8*)(qp + (size_t)qa * ND + hh * 32 + quad * 8);
    qfB[hh] = *(const bf16x8*)(qp + (size_t)qb2 * ND + hh * 32 + quad * 8);
  }

  float mA = -INFINITY, lA = 0.f, mB = -INFINITY, lB = 0.f;
  f32x4 oA[4], oB[4];
#pragma unroll
  for (int dj = 0; dj < 4; ++dj) {
    oA[dj] = (f32x4){0.f, 0.f, 0.f, 0.f};
    oB[dj] = (f32x4){0.f, 0.f, 0.f, 0.f};
  }

  for (int t0 = qA0; t0 < NT; t0 += 64) {
    // stage K[t0..t0+64)[64] and V^T[64][t0..t0+64) with XOR swizzle:
    // 16B granule c of row r stored at granule slot r*8 + (c ^ (r&7))
#pragma unroll
    for (int i = 0; i < 2; ++i) {
      const int s = w * 128 + i * 64 + lane;   // LDS granule this lane fills
      const int row = s >> 3;
      const int c = (s & 7) ^ (row & 7);       // global granule to fetch
      GLOAD_LDS16(kp + (size_t)(t0 + row) * ND + c * 8, kt + (w * 128 + i * 64) * 8);
      GLOAD_LDS16(vp + (size_t)row * NT + t0 + c * 8, vtile + (w * 128 + i * 64) * 8);
    }
    __syncthreads();

    attn_step(qfA, mA, lA, oA, qa, t0, t0 == qA0, kt, vtile, quad, l16);
    if (t0 >= qB0)
      attn_step(qfB, mB, lB, oB, qb2, t0, t0 == qB0, kt, vtile, quad, l16);

    __syncthreads();
  }

  // store O^T -> y [B,T,C]: lane owns query; d = dj*16 + quad*4 + r (contiguous r)
  const float invA = 1.0f / lA, invB = 1.0f / lB;
  const size_t baseA = ((size_t)b * NT + qa) * NC + h * 64;
  const size_t baseB = ((size_t)b * NT + qb2) * NC + h * 64;
#pragma unroll
  for (int dj = 0; dj < 4; ++dj) {
    bf16x4 va, vb;
#pragma unroll
    for (int r = 0; r < 4; ++r) {
      va[r] = (bf16_t)(oA[dj][r] * invA);
      vb[r] = (bf16_t)(oB[dj][r] * invB);
    }
    *(bf16x4*)(y + baseA + dj * 16 + quad * 4) = va;
    *(bf16x4*)(y + baseB + dj * 16 + quad * 4) = vb;
  }
}

// ---------------------------------------------------------------- out projection
__global__ __launch_bounds__(256) void out_gemm_k(const bf16_t* __restrict__ A,
                                                  const bf16_t* __restrict__ Bt,
                                                  const float* __restrict__ bias,
                                                  float* __restrict__ out) {
  __shared__ __align__(16) bf16_t lds[8192];
  const int m0 = blockIdx.y * 128, n0 = blockIdx.x * 128;
  f32x4 acc[4][4] = {};
  gemm_mainloop<NC>(A, Bt, m0, n0, acc, lds);

  const int lane = threadIdx.x & 63;
  const int w = threadIdx.x >> 6;
  const int wm = (w & 1) * 64, wn = (w >> 1) * 64;
  const int quad = lane >> 4, l16 = lane & 15;
#pragma unroll
  for (int i = 0; i < 4; ++i)
#pragma unroll
    for (int j = 0; j < 4; ++j) {
      const int n = n0 + wn + j * 16 + l16;
      const float bn = bias[n];
#pragma unroll
      for (int r = 0; r < 4; ++r) {
        const int m = m0 + wm + i * 16 + quad * 4 + r;
        out[(size_t)m * NC + n] = acc[i][j][r] + bn;
      }
    }
}

// ---------------------------------------------------------------- launch
extern "C" void kernel_launch(void* const* d_in, const int* in_sizes, int n_in,
                              void* d_out, int out_size, void* d_ws, size_t ws_size,
                              hipStream_t stream) {
  const float* x = (const float*)d_in[0];
  const float* Wqkv = (const float*)d_in[1];
  const float* bqkv = (const float*)d_in[2];
  const float* Wo = (const float*)d_in[3];
  const float* bo = (const float*)d_in[4];
  float* out = (float*)d_out;

  char* p = (char*)d_ws;
  bf16_t* xbf = (bf16_t*)p;   p += (size_t)NM * NC * sizeof(bf16_t);        // 8 MB
  bf16_t* wqkvT = (bf16_t*)p; p += (size_t)N3 * NC * sizeof(bf16_t);        // 6 MB
  bf16_t* woT = (bf16_t*)p;   p += (size_t)NC * NC * sizeof(bf16_t);        // 2 MB
  bf16_t* qb = (bf16_t*)p;    p += (size_t)NB * NH * NT * ND * sizeof(bf16_t); // 8 MB
  bf16_t* kb = (bf16_t*)p;    p += (size_t)NB * NH * NT * ND * sizeof(bf16_t); // 8 MB
  bf16_t* vtb = (bf16_t*)p;   p += (size_t)NB * NH * ND * NT * sizeof(bf16_t); // 8 MB
  bf16_t* yb = (bf16_t*)p;    p += (size_t)NM * NC * sizeof(bf16_t);        // 8 MB

  hipLaunchKernelGGL(cast_f32_bf16_k, dim3(NM * NC / 1024), dim3(256), 0, stream,
                     x, xbf, NM * NC);
  hipLaunchKernelGGL(transpose_cast_k, dim3(N3 / 32, NC / 32), dim3(256), 0, stream,
                     Wqkv, wqkvT, NC, N3);
  hipLaunchKernelGGL(transpose_cast_k, dim3(NC / 32, NC / 32), dim3(256), 0, stream,
                     Wo, woT, NC, NC);
  hipLaunchKernelGGL(qkv_gemm_k, dim3(N3 / 128, NM / 128), dim3(256), 0, stream,
                     xbf, wqkvT, bqkv, qb, kb, vtb);
  hipLaunchKernelGGL(attn_k, dim3(32 * 16), dim3(256), 0, stream,
                     qb, kb, vtb, yb);
  hipLaunchKernelGGL(out_gemm_k, dim3(NC / 128, NM / 128), dim3(256), 0, stream,
                     yb, woT, bo, out);
}